// Round 1
// 4352.287 us; speedup vs baseline: 1.0062x; 1.0062x over previous
//
#include <hip/hip_runtime.h>
#include <stdint.h>

// ---------------------------------------------------------------------------
// DynResNet: u,v are (provably) constant; s += H*u^T dY v; x = u s v^T.
// Per step: Y = X*W^T (bf16 MFMA GEMM, W streamed via global_load_lds),
// then per-sample MFMA chain R=dY*v, dS=u^T R, inc=u*dS*v^T, x += H*inc (fp32 regs).
// Outputs are FP32 (reference dtype).
//
// R1 change: X_transformed is written t-major per sample (contiguous 3136 B
// per (t,sample) -> no partial-line scatter, no RMW fills, no L3 thrash of W),
// then dyn_transp2 transposes each sample's 33x784 tile in place via LDS.
// TR/bf16 staging path deleted (workspace only needs WT).
// ---------------------------------------------------------------------------

#define H_STEP 0.001f

typedef float  f32x4  __attribute__((ext_vector_type(4)));
typedef __bf16 bf16x8 __attribute__((ext_vector_type(8)));

__device__ __forceinline__ unsigned short f2bf(float f){
  unsigned u = __float_as_uint(f);
  u += 0x7FFFu + ((u >> 16) & 1u);        // RNE (finite data only)
  return (unsigned short)(u >> 16);
}
__device__ __forceinline__ float bf2f(unsigned short h){
  return __uint_as_float(((unsigned)h) << 16);
}

// W tiling: 33 layers x 50 chunks; chunk = [416 n][40 k] bf16 (32 real k + 8 pad)
#define CHUNK_ROWS 416
#define CHUNK_RB   40
#define CHUNK_ELEMS (CHUNK_ROWS*CHUNK_RB)        // 16640
#define CHUNK_BYTES (CHUNK_ELEMS*2)              // 33280
#define NCHUNKS 50
#define NLAYER  33
#define WT_ELEMS ((size_t)NLAYER*NCHUNKS*CHUNK_ELEMS)
#define WT_BYTES (WT_ELEMS*2)                    // 54,912,000

// LDS byte offsets (total 154,880 <= 163,840)
#define WBUF0_B 0          // 34,816 (W stage buf A; dY [16][28][32] bf16 aliases; init scratch)
#define WBUF1_B 34816      // 34,816 (W stage buf B; RT [16][16][40] + G1 [16][28][16] alias)
#define XB_B    69632      // [16][808] bf16 GEMM A (x), K padded to 800
#define UA_B    95488      // [16][28][16] bf16  u[i][a]    (A for G1)
#define UA2_B   109824     // [16][10][40] bf16  u^T[a][i]  (A for dS)
#define VB2_B   122624     // [16][10][40] bf16  vh[b][j]   (B for R)
#define VTB_B   135424     // [16][28][16] bf16  v[j][b]    (B for G2)
#define DSB_B   149760     // [16][10][16] bf16  dS^T[b][a] (B for G1); logits scratch
#define LDS_TOTAL 154880
#define RT_B (WBUF1_B)
#define G1_B (WBUF1_B + 20480)

// per-sample transformed-output region: 784*33 fp32
#define SAMP_ELEMS (784*33)                      // 25872
#define TRANSP_LDS (SAMP_ELEMS*4)                // 103,488

__device__ __forceinline__ void gl16(const void* g, void* l){
  __builtin_amdgcn_global_load_lds(
      (const __attribute__((address_space(1))) unsigned int*)g,
      (__attribute__((address_space(3))) unsigned int*)l, 16, 0, 0);
}

// ---------------- prep: tile W0/Ws into bf16 B-fragment layout ----------------
__global__ void dyn_prep(const float* __restrict__ W0, const float* __restrict__ Ws,
                         unsigned short* __restrict__ WT)
{
  const int total = NLAYER*NCHUNKS*CHUNK_ELEMS;
  for (int e = blockIdx.x*256 + threadIdx.x; e < total; e += gridDim.x*256){
    int c   = e / CHUNK_ELEMS;
    int off = e - c*CHUNK_ELEMS;
    int n_  = off / CHUNK_RB;
    int kk  = off - n_*CHUNK_RB;
    int l   = c / NCHUNKS;
    int r   = c - l*NCHUNKS;
    int nh  = r / 25;
    int kc  = r - nh*25;
    int n   = nh*416 + n_;
    int qk  = kc*32 + kk;
    float v = 0.f;
    if (kk < 32 && n < 784 && qk < 784){
      const float* W = (l == 0) ? W0 : (Ws + (size_t)(l-1)*614656);
      v = W[(size_t)n*784 + qk];
    }
    WT[e] = f2bf(v);
  }
}

// ---------------- main persistent kernel ----------------
__global__ void __launch_bounds__(256,1)
dyn_net(const float* __restrict__ X, const float* __restrict__ bs,
        const float* __restrict__ Wc, const float* __restrict__ bc,
        const unsigned short* __restrict__ WT, float* __restrict__ OUT)
{
  extern __shared__ char smem[];
  unsigned short* s16 = (unsigned short*)smem;
  const int tid = threadIdx.x;
  const int w = tid >> 6, lane = tid & 63, quad = lane >> 4, col = lane & 15;
  const int blk = blockIdx.x;

  for (int i = tid; i < LDS_TOTAL/4; i += 256) ((unsigned int*)smem)[i] = 0u;
  __syncthreads();

  // static per-sample operand buffers (u,v never change)
  for (int e = tid; e < 16*28*16; e += 256){            // uA [m][i][a16]
    int m = e / 448, r = e % 448, i = r >> 4, a = r & 15;
    float v = (a < 10) ? X[(size_t)(blk*16+m)*840 + i*10 + a] : 0.f;
    s16[UA_B/2 + e] = f2bf(v);
  }
  for (int e = tid; e < 16*10*40; e += 256){            // uA2 [m][a][i40]
    int m = e / 400, r = e % 400, a = r / 40, i = r % 40;
    float v = (i < 28) ? X[(size_t)(blk*16+m)*840 + i*10 + a] : 0.f;
    s16[UA2_B/2 + e] = f2bf(v);
  }
  for (int e = tid; e < 16*10*40; e += 256){            // vB2 [m][b][j40] = vh[b][j]
    int m = e / 400, r = e % 400, b = r / 40, j = r % 40;
    float v = (j < 28) ? X[(size_t)(blk*16+m)*840 + 560 + b*28 + j] : 0.f;
    s16[VB2_B/2 + e] = f2bf(v);
  }
  for (int e = tid; e < 16*28*16; e += 256){            // vTB [m][j][b16] = vh[b][j]
    int m = e / 448, r = e % 448, j = r >> 4, b = r & 15;
    float v = (b < 10) ? X[(size_t)(blk*16+m)*840 + 560 + b*28 + j] : 0.f;
    s16[VTB_B/2 + e] = f2bf(v);
  }
  __syncthreads();

  // x_init = u*s0*vh in exact fp32; xr = register fp32 x master
  float xr[4][2][2][4];
  for (int q = 0; q < 4; ++q){
    int m = w*4 + q;
    int gm = blk*16 + m;
    float* scr = (float*)(smem + WBUF0_B) + w*2048;     // 8KB/wave scratch
    for (int e = lane; e < 840; e += 64) scr[e] = X[(size_t)gm*840 + e];
    __syncthreads();
    float* T = scr + 840;                               // T = u@s0 (28x10)
    for (int it = 0; it < 5; ++it){
      int e = lane + it*64;
      if (e < 280){
        int i = e / 10, b = e % 10;
        float acc = 0.f;
        for (int a = 0; a < 10; ++a) acc += scr[i*10+a] * scr[280 + a*10 + b];
        T[e] = acc;
      }
    }
    __syncthreads();
    #pragma unroll
    for (int mt = 0; mt < 2; ++mt)
    #pragma unroll
    for (int nt = 0; nt < 2; ++nt)
    #pragma unroll
    for (int r = 0; r < 4; ++r){
      int i = mt*16 + quad*4 + r;
      int j = nt*16 + col;
      float acc = 0.f;
      if (i < 28 && j < 28){
        for (int b = 0; b < 10; ++b) acc += T[i*10+b] * scr[560 + b*28 + j];
        s16[XB_B/2 + m*808 + i*28 + j] = f2bf(acc);
      }
      xr[q][mt][nt][r] = acc;
    }
    __syncthreads();
  }

  const int cnt0  = (w < 2) ? 7 : 6;                    // n-tiles per wave per half
  const int tbase = (w==0) ? 0 : (w==1) ? 7 : (w==2) ? 14 : 20;
  const float Hs = H_STEP;

  for (int t = 0; t < NLAYER; ++t){
    const unsigned short* WL = WT + (size_t)t*NCHUNKS*CHUNK_ELEMS;
    f32x4 acc[2][7];
    #pragma unroll
    for (int h = 0; h < 2; ++h)
      #pragma unroll
      for (int p = 0; p < 7; ++p) acc[h][p] = (f32x4){0.f,0.f,0.f,0.f};

    // prologue: stage chunk 0 -> buf0
    {
      const char* g = (const char*)WL;
      char* l = smem + WBUF0_B;
      #pragma unroll
      for (int rnd = 0; rnd < 8; ++rnd)
        gl16(g + rnd*4096 + w*1024 + lane*16, l + rnd*4096 + w*1024);
      if (tid < 32) gl16(g + 32768 + lane*16, l + 32768);
    }

    #pragma unroll 1
    for (int nh = 0; nh < 2; ++nh){
      #pragma unroll 1
      for (int kc = 0; kc < 25; ++kc){
        int c = nh*25 + kc;
        __syncthreads();                                // stage(c) drained; prev compute done
        if (c < 49){
          int c1 = c + 1;
          const char* g = (const char*)(WL + (size_t)c1*CHUNK_ELEMS);
          char* l = smem + ((c1 & 1) ? WBUF1_B : WBUF0_B);
          #pragma unroll
          for (int rnd = 0; rnd < 8; ++rnd)
            gl16(g + rnd*4096 + w*1024 + lane*16, l + rnd*4096 + w*1024);
          if (tid < 32) gl16(g + 32768 + lane*16, l + 32768);
        }
        const unsigned short* wb =
            (const unsigned short*)(smem + ((c & 1) ? WBUF1_B : WBUF0_B));
        bf16x8 afrag = *(const bf16x8*)(s16 + XB_B/2 + col*808 + kc*32 + quad*8);
        #pragma unroll
        for (int p = 0; p < 7; ++p){
          if (p < cnt0){
            int nloc = (tbase + p)*16 + col;
            bf16x8 bfrag = *(const bf16x8*)(wb + nloc*40 + quad*8);
            acc[nh][p] = __builtin_amdgcn_mfma_f32_16x16x32_bf16(afrag, bfrag, acc[nh][p], 0,0,0);
          }
        }
      }
    }

    // epilogue: bias/relu, write dY bf16 into WBUF0
    unsigned short* dy = (unsigned short*)(smem + WBUF0_B);
    #pragma unroll 1
    for (int nh = 0; nh < 2; ++nh){
      #pragma unroll
      for (int p = 0; p < 7; ++p){
        if (p < cnt0){
          int n = nh*416 + (tbase+p)*16 + col;
          if (n < 784){
            int i = n / 28, j = n % 28;
            float bias = (t > 0) ? bs[(size_t)(t-1)*784 + n] : 0.f;
            #pragma unroll
            for (int r = 0; r < 4; ++r){
              float y = acc[nh][p][r] + bias;
              if (t > 0) y = fmaxf(y, 0.f);
              int m = quad*4 + r;
              dy[m*896 + i*32 + j] = f2bf(y);
            }
          }
        }
      }
    }
    __syncthreads();                                    // dY visible to all waves

    // small stages per wave (samples w*4..w*4+3)
    #pragma unroll 1
    for (int q = 0; q < 4; ++q){
      int m = w*4 + q;
      bf16x8 zfrag = {0,0,0,0,0,0,0,0};
      const unsigned short* dys = dy + m*896;
      // R = dY @ v  -> RT[b][i]
      bf16x8 bfA = zfrag;
      if (col < 10) bfA = *(const bf16x8*)(s16 + VB2_B/2 + m*400 + col*40 + quad*8);
      unsigned short* rt = s16 + RT_B/2 + m*640;
      #pragma unroll
      for (int mt = 0; mt < 2; ++mt){
        bf16x8 afA = *(const bf16x8*)(dys + (col + 16*mt)*32 + quad*8);
        f32x4 cR = {0.f,0.f,0.f,0.f};
        cR = __builtin_amdgcn_mfma_f32_16x16x32_bf16(afA, bfA, cR, 0,0,0);
        int i0 = mt*16 + quad*4;
        if (i0 < 28){
          unsigned short* p = rt + col*40 + i0;
          p[0]=f2bf(cR[0]); p[1]=f2bf(cR[1]); p[2]=f2bf(cR[2]); p[3]=f2bf(cR[3]);
        }
      }
      // dS = u^T @ R
      bf16x8 afB = zfrag;
      if (col < 10) afB = *(const bf16x8*)(s16 + UA2_B/2 + m*400 + col*40 + quad*8);
      bf16x8 bfB = *(const bf16x8*)(rt + col*40 + quad*8);
      f32x4 cS = {0.f,0.f,0.f,0.f};
      cS = __builtin_amdgcn_mfma_f32_16x16x32_bf16(afB, bfB, cS, 0,0,0);
      unsigned short* dsb = s16 + DSB_B/2 + m*160;      // dS^T[b][a]
      if (col < 10){
        unsigned short* p = dsb + col*16 + quad*4;
        p[0]=f2bf(cS[0]); p[1]=f2bf(cS[1]); p[2]=f2bf(cS[2]); p[3]=f2bf(cS[3]);
      }
      // G1 = u @ dS  (K=16 via quads 0,1)
      bf16x8 bfG = zfrag;
      if (quad < 2 && col < 10) bfG = *(const bf16x8*)(dsb + col*16 + quad*8);
      const unsigned short* ua = s16 + UA_B/2 + m*448;
      unsigned short* g1 = s16 + G1_B/2 + m*448;
      #pragma unroll
      for (int mt = 0; mt < 2; ++mt){
        int row = col + 16*mt;
        bf16x8 afG = zfrag;
        if (quad < 2 && row < 28) afG = *(const bf16x8*)(ua + row*16 + quad*8);
        f32x4 cG = {0.f,0.f,0.f,0.f};
        cG = __builtin_amdgcn_mfma_f32_16x16x32_bf16(afG, bfG, cG, 0,0,0);
        int i0 = mt*16 + quad*4;
        #pragma unroll
        for (int r = 0; r < 4; ++r)
          if (i0 + r < 28) g1[(i0+r)*16 + col] = f2bf(cG[r]);
      }
      // G2 = G1 @ v^T ; x += H*G2 (fp32 regs); write xb + t-major transformed out
      const unsigned short* vtb = s16 + VTB_B/2 + m*448;
      bf16x8 bt[2];
      #pragma unroll
      for (int nt = 0; nt < 2; ++nt){
        bt[nt] = zfrag;
        int n = col + 16*nt;
        if (quad < 2 && n < 28) bt[nt] = *(const bf16x8*)(vtb + n*16 + quad*8);
      }
      int gm = blk*16 + m;
      // contiguous per (t,sample): coalesced full-line stores, amp ~1.0
      float* outg = OUT + 40960 + (size_t)gm*SAMP_ELEMS + (size_t)t*784;
      #pragma unroll
      for (int mt = 0; mt < 2; ++mt){
        int row = col + 16*mt;
        bf16x8 afX = zfrag;
        if (quad < 2 && row < 28) afX = *(const bf16x8*)(g1 + row*16 + quad*8);
        #pragma unroll
        for (int nt = 0; nt < 2; ++nt){
          f32x4 cX = {0.f,0.f,0.f,0.f};
          cX = __builtin_amdgcn_mfma_f32_16x16x32_bf16(afX, bt[nt], cX, 0,0,0);
          int i0 = mt*16 + quad*4;
          int j = nt*16 + col;
          if (j < 28){
            #pragma unroll
            for (int r = 0; r < 4; ++r){
              int i = i0 + r;
              if (i < 28){
                float xn = xr[q][mt][nt][r] + Hs * cX[r];
                xr[q][mt][nt][r] = xn;
                s16[XB_B/2 + m*808 + i*28 + j] = f2bf(xn);
                outg[i*28 + j] = xn;
              }
            }
          }
        }
      }
    }
    __syncthreads();                                    // step end
  }

  // classifier + softmax (fp32 outputs)
  float* lg = (float*)(smem + DSB_B);
  if (tid < 160){
    int m = tid / 10, c = tid % 10;
    float accv = bc[c];
    const unsigned short* xbp = s16 + XB_B/2 + m*808;
    for (int p = 0; p < 784; ++p)
      accv += bf2f(xbp[p]) * Wc[(size_t)c*784 + p];
    lg[tid] = accv;
  }
  __syncthreads();
  if (tid < 16){
    int gm = blk*16 + tid;
    float* l = lg + tid*10;
    float mx = l[0];
    for (int c2 = 1; c2 < 10; ++c2) mx = fmaxf(mx, l[c2]);
    float s = 0.f, ex[10];
    for (int c2 = 0; c2 < 10; ++c2){ ex[c2] = expf(l[c2]-mx); s += ex[c2]; }
    float inv = 1.f / s;
    for (int c2 = 0; c2 < 10; ++c2){
      OUT[(size_t)gm*10 + c2]         = ex[c2]*inv;   // X_predicted (fp32)
      OUT[20480 + (size_t)gm*10 + c2] = l[c2];        // X_classified (fp32)
    }
  }
}

// ---------------- per-sample in-place transpose: [t][p] -> [p][t] (fp32) ------
// One block per sample; 33x784 fp32 tile lives in LDS (101 KB). Stride 33 is
// odd (33 % 32 == 1) so the transposed LDS writes are bank-conflict-free.
__global__ void dyn_transp2(float* __restrict__ OUT)
{
  extern __shared__ float tile[];                 // [784][33] indexed p*33+t
  const int gm = blockIdx.x, tid = threadIdx.x;
  float* base = OUT + 40960 + (size_t)gm*SAMP_ELEMS;
  for (int idx = tid; idx < SAMP_ELEMS; idx += 256){
    int t = idx / 784, p = idx - t*784;
    tile[p*33 + t] = base[idx];                   // coalesced read, cf-free write
  }
  __syncthreads();
  for (int idx = tid; idx < SAMP_ELEMS; idx += 256)
    base[idx] = tile[idx];                        // cf-free read, coalesced write
}

// ---------------- launch ----------------
extern "C" void kernel_launch(void* const* d_in, const int* in_sizes, int n_in,
                              void* d_out, int out_size, void* d_ws, size_t ws_size,
                              hipStream_t stream)
{
  const float* X  = (const float*)d_in[0];
  const float* W0 = (const float*)d_in[1];
  const float* Ws = (const float*)d_in[2];
  const float* bs = (const float*)d_in[3];
  const float* Wc = (const float*)d_in[4];
  const float* bc = (const float*)d_in[5];
  unsigned short* WT = (unsigned short*)d_ws;
  float* OUT = (float*)d_out;

  (void)hipFuncSetAttribute((const void*)dyn_net,
        hipFuncAttributeMaxDynamicSharedMemorySize, LDS_TOTAL);
  (void)hipFuncSetAttribute((const void*)dyn_transp2,
        hipFuncAttributeMaxDynamicSharedMemorySize, TRANSP_LDS);

  dyn_prep<<<dim3(8192), dim3(256), 0, stream>>>(W0, Ws, WT);
  dyn_net<<<dim3(128), dim3(256), LDS_TOTAL, stream>>>(X, bs, Wc, bc, WT, OUT);
  dyn_transp2<<<dim3(2048), dim3(256), TRANSP_LDS, stream>>>(OUT);
}

// Round 3
// 1247.211 us; speedup vs baseline: 3.5114x; 3.4896x over previous
//
#include <hip/hip_runtime.h>
#include <stdint.h>

// ---------------------------------------------------------------------------
// DynResNet: u,v are (provably) constant; s += H*u^T dY v; x = u s v^T.
// Per step: Y = X*W^T (bf16 MFMA GEMM), then per-sample MFMA chain
// R=dY*v, dS=u^T R, inc=u*dS*v^T, x += H*inc (fp32 regs). FP32 outputs.
//
// R2: W streamed global->VGPR as per-wave 1KB fragments (no LDS staging, no
// barriers in K-loop). R3 fix: re-zero WBUF0 (dY buffer) after x_init — the
// fp32 init scratch left NaN-pattern bf16 garbage in dY's padding columns
// (j=28..31), which the R-stage MFMA consumes as A-elements; NaN*0 = NaN.
// Previously W-staging incidentally overwrote that region with finite values.
// ---------------------------------------------------------------------------

#define H_STEP 0.001f

typedef float  f32x4  __attribute__((ext_vector_type(4)));
typedef __bf16 bf16x8 __attribute__((ext_vector_type(8)));

__device__ __forceinline__ unsigned short f2bf(float f){
  unsigned u = __float_as_uint(f);
  u += 0x7FFFu + ((u >> 16) & 1u);        // RNE (finite data only)
  return (unsigned short)(u >> 16);
}
__device__ __forceinline__ float bf2f(unsigned short h){
  return __uint_as_float(((unsigned)h) << 16);
}

// W fragment tiling: 33 layers x 25 kc x 52 n-tiles; fragment = 1KB
// (64 lanes x 16B). lane(quad,col): n = p*16+col, k = kc*32+quad*8+j (j=0..7).
#define NLAYER  33
#define NKC     25
#define NTILE   52
#define FRAG_B  1024
#define TILES_PER_WAVE 13
#define WT2_SHORTS ((size_t)NLAYER*NKC*NTILE*512)   // 21,964,800 (43.9 MB)

// LDS byte offsets (total 154,880 <= 163,840)
#define WBUF0_B 0          // 34,816: init scratch; dY [16][28][32] bf16
#define WBUF1_B 34816      // 34,816: RT [16][16][40] + G1 [16][28][16] alias
#define XB_B    69632      // [16][808] bf16 GEMM A (x), K padded to 800
#define UA_B    95488      // [16][28][16] bf16  u[i][a]    (A for G1)
#define UA2_B   109824     // [16][10][40] bf16  u^T[a][i]  (A for dS)
#define VB2_B   122624     // [16][10][40] bf16  vh[b][j]   (B for R)
#define VTB_B   135424     // [16][28][16] bf16  v[j][b]    (B for G2)
#define DSB_B   149760     // [16][10][16] bf16  dS^T[b][a] (B for G1); logits scratch
#define LDS_TOTAL 154880
#define RT_B (WBUF1_B)
#define G1_B (WBUF1_B + 20480)

// per-sample transformed-output region: 784*33 fp32
#define SAMP_ELEMS (784*33)                      // 25872
#define TRANSP_LDS (SAMP_ELEMS*4)                // 103,488

// ---------------- prep: tile W0/Ws into per-wave bf16 B fragments -------------
__global__ void dyn_prep(const float* __restrict__ W0, const float* __restrict__ Ws,
                         unsigned short* __restrict__ WT)
{
  const size_t total = WT2_SHORTS;
  for (size_t e = (size_t)blockIdx.x*256 + threadIdx.x; e < total; e += (size_t)gridDim.x*256){
    int s    = (int)(e & 511);          // short within fragment
    int lane = s >> 3, j = s & 7;
    size_t f = e >> 9;                  // fragment index = (t*25 + kc)*52 + p
    int p  = (int)(f % NTILE);
    size_t r = f / NTILE;
    int kc = (int)(r % NKC);
    int t  = (int)(r / NKC);
    int n  = p*16 + (lane & 15);
    int k  = kc*32 + (lane >> 4)*8 + j;
    float v = 0.f;
    if (n < 784 && k < 784){
      const float* W = (t == 0) ? W0 : (Ws + (size_t)(t-1)*614656);
      v = W[(size_t)n*784 + k];
    }
    WT[e] = f2bf(v);
  }
}

// ---------------- main persistent kernel ----------------
__global__ void __launch_bounds__(256,1)
dyn_net(const float* __restrict__ X, const float* __restrict__ bs,
        const float* __restrict__ Wc, const float* __restrict__ bc,
        const unsigned short* __restrict__ WT, float* __restrict__ OUT)
{
  extern __shared__ char smem[];
  unsigned short* s16 = (unsigned short*)smem;
  const int tid = threadIdx.x;
  const int w = tid >> 6, lane = tid & 63, quad = lane >> 4, col = lane & 15;
  const int blk = blockIdx.x;

  for (int i = tid; i < LDS_TOTAL/4; i += 256) ((unsigned int*)smem)[i] = 0u;
  __syncthreads();

  // static per-sample operand buffers (u,v never change)
  for (int e = tid; e < 16*28*16; e += 256){            // uA [m][i][a16]
    int m = e / 448, r = e % 448, i = r >> 4, a = r & 15;
    float v = (a < 10) ? X[(size_t)(blk*16+m)*840 + i*10 + a] : 0.f;
    s16[UA_B/2 + e] = f2bf(v);
  }
  for (int e = tid; e < 16*10*40; e += 256){            // uA2 [m][a][i40]
    int m = e / 400, r = e % 400, a = r / 40, i = r % 40;
    float v = (i < 28) ? X[(size_t)(blk*16+m)*840 + i*10 + a] : 0.f;
    s16[UA2_B/2 + e] = f2bf(v);
  }
  for (int e = tid; e < 16*10*40; e += 256){            // vB2 [m][b][j40] = vh[b][j]
    int m = e / 400, r = e % 400, b = r / 40, j = r % 40;
    float v = (j < 28) ? X[(size_t)(blk*16+m)*840 + 560 + b*28 + j] : 0.f;
    s16[VB2_B/2 + e] = f2bf(v);
  }
  for (int e = tid; e < 16*28*16; e += 256){            // vTB [m][j][b16] = vh[b][j]
    int m = e / 448, r = e % 448, j = r >> 4, b = r & 15;
    float v = (b < 10) ? X[(size_t)(blk*16+m)*840 + 560 + b*28 + j] : 0.f;
    s16[VTB_B/2 + e] = f2bf(v);
  }
  __syncthreads();

  // x_init = u*s0*vh in exact fp32; xr = register fp32 x master
  float xr[4][2][2][4];
  for (int q = 0; q < 4; ++q){
    int m = w*4 + q;
    int gm = blk*16 + m;
    float* scr = (float*)(smem + WBUF0_B) + w*2048;     // 8KB/wave scratch
    for (int e = lane; e < 840; e += 64) scr[e] = X[(size_t)gm*840 + e];
    __syncthreads();
    float* T = scr + 840;                               // T = u@s0 (28x10)
    for (int it = 0; it < 5; ++it){
      int e = lane + it*64;
      if (e < 280){
        int i = e / 10, b = e % 10;
        float acc = 0.f;
        for (int a = 0; a < 10; ++a) acc += scr[i*10+a] * scr[280 + a*10 + b];
        T[e] = acc;
      }
    }
    __syncthreads();
    #pragma unroll
    for (int mt = 0; mt < 2; ++mt)
    #pragma unroll
    for (int nt = 0; nt < 2; ++nt)
    #pragma unroll
    for (int r = 0; r < 4; ++r){
      int i = mt*16 + quad*4 + r;
      int j = nt*16 + col;
      float acc = 0.f;
      if (i < 28 && j < 28){
        for (int b = 0; b < 10; ++b) acc += T[i*10+b] * scr[560 + b*28 + j];
        s16[XB_B/2 + m*808 + i*28 + j] = f2bf(acc);
      }
      xr[q][mt][nt][r] = acc;
    }
    __syncthreads();
  }

  // R3 FIX: re-zero WBUF0 (dY buffer incl. padding cols j=28..31 and tail).
  // The fp32 x_init scratch left NaN-pattern bf16 garbage; R-stage MFMA reads
  // those as A-elements and NaN*0 = NaN would poison the contraction. The
  // epilogue only ever writes j<28, so one zeroing keeps padding clean forever.
  for (int i = tid; i < 34816/4; i += 256)
    ((unsigned int*)(smem + WBUF0_B))[i] = 0u;
  __syncthreads();

  const float Hs = H_STEP;
  const int P0 = w*TILES_PER_WAVE;                      // wave's n-tile base

  for (int t = 0; t < NLAYER; ++t){
    // --- GEMM: Y = x @ W^T, W streamed global->VGPR, no LDS, no barriers ---
    const char* WLb = (const char*)WT
        + ((size_t)t*NKC*NTILE + (size_t)P0)*FRAG_B + (size_t)lane*16;
    // fragment (kc,p): WLb + kc*(NTILE*FRAG_B) + p*FRAG_B

    f32x4 acc[TILES_PER_WAVE];
    #pragma unroll
    for (int p = 0; p < TILES_PER_WAVE; ++p) acc[p] = (f32x4){0.f,0.f,0.f,0.f};

    float biasr[TILES_PER_WAVE];                        // hoisted bias loads
    #pragma unroll
    for (int p = 0; p < TILES_PER_WAVE; ++p){
      int n = (P0+p)*16 + col;
      float bv = 0.f;
      if (t > 0 && n < 784) bv = bs[(size_t)(t-1)*784 + n];
      biasr[p] = bv;
    }

    bf16x8 wfA[TILES_PER_WAVE], wfB[TILES_PER_WAVE];
    #pragma unroll
    for (int p = 0; p < TILES_PER_WAVE; ++p)
      wfA[p] = *(const bf16x8*)(WLb + (size_t)p*FRAG_B);

    #pragma unroll 1
    for (int kc = 0; kc < NKC; kc += 2){
      if (kc+1 < NKC){
        const char* nb = WLb + (size_t)(kc+1)*(NTILE*FRAG_B);
        #pragma unroll
        for (int p = 0; p < TILES_PER_WAVE; ++p)
          wfB[p] = *(const bf16x8*)(nb + (size_t)p*FRAG_B);
      }
      bf16x8 af = *(const bf16x8*)(s16 + XB_B/2 + col*808 + kc*32 + quad*8);
      #pragma unroll
      for (int p = 0; p < TILES_PER_WAVE; ++p)
        acc[p] = __builtin_amdgcn_mfma_f32_16x16x32_bf16(af, wfA[p], acc[p], 0,0,0);
      if (kc+1 < NKC){
        if (kc+2 < NKC){
          const char* nb2 = WLb + (size_t)(kc+2)*(NTILE*FRAG_B);
          #pragma unroll
          for (int p = 0; p < TILES_PER_WAVE; ++p)
            wfA[p] = *(const bf16x8*)(nb2 + (size_t)p*FRAG_B);
        }
        bf16x8 af2 = *(const bf16x8*)(s16 + XB_B/2 + col*808 + (kc+1)*32 + quad*8);
        #pragma unroll
        for (int p = 0; p < TILES_PER_WAVE; ++p)
          acc[p] = __builtin_amdgcn_mfma_f32_16x16x32_bf16(af2, wfB[p], acc[p], 0,0,0);
      }
    }

    // epilogue: bias/relu, write dY bf16 into WBUF0
    unsigned short* dy = (unsigned short*)(smem + WBUF0_B);
    #pragma unroll
    for (int p = 0; p < TILES_PER_WAVE; ++p){
      int n = (P0+p)*16 + col;
      if (n < 784){
        int i = n / 28, j = n % 28;
        #pragma unroll
        for (int r = 0; r < 4; ++r){
          float y = acc[p][r] + biasr[p];
          if (t > 0) y = fmaxf(y, 0.f);
          dy[(quad*4+r)*896 + i*32 + j] = f2bf(y);
        }
      }
    }
    __syncthreads();                                    // dY visible to all waves

    // small stages per wave (samples w*4..w*4+3)
    #pragma unroll 1
    for (int q = 0; q < 4; ++q){
      int m = w*4 + q;
      bf16x8 zfrag = {0,0,0,0,0,0,0,0};
      const unsigned short* dys = dy + m*896;
      // R = dY @ v  -> RT[b][i]
      bf16x8 bfA = zfrag;
      if (col < 10) bfA = *(const bf16x8*)(s16 + VB2_B/2 + m*400 + col*40 + quad*8);
      unsigned short* rt = s16 + RT_B/2 + m*640;
      #pragma unroll
      for (int mt = 0; mt < 2; ++mt){
        bf16x8 afA = *(const bf16x8*)(dys + (col + 16*mt)*32 + quad*8);
        f32x4 cR = {0.f,0.f,0.f,0.f};
        cR = __builtin_amdgcn_mfma_f32_16x16x32_bf16(afA, bfA, cR, 0,0,0);
        int i0 = mt*16 + quad*4;
        if (i0 < 28){
          unsigned short* p = rt + col*40 + i0;
          p[0]=f2bf(cR[0]); p[1]=f2bf(cR[1]); p[2]=f2bf(cR[2]); p[3]=f2bf(cR[3]);
        }
      }
      // dS = u^T @ R
      bf16x8 afB = zfrag;
      if (col < 10) afB = *(const bf16x8*)(s16 + UA2_B/2 + m*400 + col*40 + quad*8);
      bf16x8 bfB = *(const bf16x8*)(rt + col*40 + quad*8);
      f32x4 cS = {0.f,0.f,0.f,0.f};
      cS = __builtin_amdgcn_mfma_f32_16x16x32_bf16(afB, bfB, cS, 0,0,0);
      unsigned short* dsb = s16 + DSB_B/2 + m*160;      // dS^T[b][a]
      if (col < 10){
        unsigned short* p = dsb + col*16 + quad*4;
        p[0]=f2bf(cS[0]); p[1]=f2bf(cS[1]); p[2]=f2bf(cS[2]); p[3]=f2bf(cS[3]);
      }
      // G1 = u @ dS  (K=16 via quads 0,1)
      bf16x8 bfG = zfrag;
      if (quad < 2 && col < 10) bfG = *(const bf16x8*)(dsb + col*16 + quad*8);
      const unsigned short* ua = s16 + UA_B/2 + m*448;
      unsigned short* g1 = s16 + G1_B/2 + m*448;
      #pragma unroll
      for (int mt = 0; mt < 2; ++mt){
        int row = col + 16*mt;
        bf16x8 afG = zfrag;
        if (quad < 2 && row < 28) afG = *(const bf16x8*)(ua + row*16 + quad*8);
        f32x4 cG = {0.f,0.f,0.f,0.f};
        cG = __builtin_amdgcn_mfma_f32_16x16x32_bf16(afG, bfG, cG, 0,0,0);
        int i0 = mt*16 + quad*4;
        #pragma unroll
        for (int r = 0; r < 4; ++r)
          if (i0 + r < 28) g1[(i0+r)*16 + col] = f2bf(cG[r]);
      }
      // G2 = G1 @ v^T ; x += H*G2 (fp32 regs); write xb + t-major transformed out
      const unsigned short* vtb = s16 + VTB_B/2 + m*448;
      bf16x8 bt[2];
      #pragma unroll
      for (int nt = 0; nt < 2; ++nt){
        bt[nt] = zfrag;
        int n = col + 16*nt;
        if (quad < 2 && n < 28) bt[nt] = *(const bf16x8*)(vtb + n*16 + quad*8);
      }
      int gm = blk*16 + m;
      // contiguous per (t,sample): coalesced stores, transposed later
      float* outg = OUT + 40960 + (size_t)gm*SAMP_ELEMS + (size_t)t*784;
      #pragma unroll
      for (int mt = 0; mt < 2; ++mt){
        int row = col + 16*mt;
        bf16x8 afX = zfrag;
        if (quad < 2 && row < 28) afX = *(const bf16x8*)(g1 + row*16 + quad*8);
        #pragma unroll
        for (int nt = 0; nt < 2; ++nt){
          f32x4 cX = {0.f,0.f,0.f,0.f};
          cX = __builtin_amdgcn_mfma_f32_16x16x32_bf16(afX, bt[nt], cX, 0,0,0);
          int i0 = mt*16 + quad*4;
          int j = nt*16 + col;
          if (j < 28){
            #pragma unroll
            for (int r = 0; r < 4; ++r){
              int i = i0 + r;
              if (i < 28){
                float xn = xr[q][mt][nt][r] + Hs * cX[r];
                xr[q][mt][nt][r] = xn;
                s16[XB_B/2 + m*808 + i*28 + j] = f2bf(xn);
                outg[i*28 + j] = xn;
              }
            }
          }
        }
      }
    }
    __syncthreads();                                    // step end (XB handoff)
  }

  // classifier + softmax (fp32 outputs)
  float* lg = (float*)(smem + DSB_B);
  if (tid < 160){
    int m = tid / 10, c = tid % 10;
    float accv = bc[c];
    const unsigned short* xbp = s16 + XB_B/2 + m*808;
    for (int p = 0; p < 784; ++p)
      accv += bf2f(xbp[p]) * Wc[(size_t)c*784 + p];
    lg[tid] = accv;
  }
  __syncthreads();
  if (tid < 16){
    int gm = blk*16 + tid;
    float* l = lg + tid*10;
    float mx = l[0];
    for (int c2 = 1; c2 < 10; ++c2) mx = fmaxf(mx, l[c2]);
    float s = 0.f, ex[10];
    for (int c2 = 0; c2 < 10; ++c2){ ex[c2] = expf(l[c2]-mx); s += ex[c2]; }
    float inv = 1.f / s;
    for (int c2 = 0; c2 < 10; ++c2){
      OUT[(size_t)gm*10 + c2]         = ex[c2]*inv;   // X_predicted (fp32)
      OUT[20480 + (size_t)gm*10 + c2] = l[c2];        // X_classified (fp32)
    }
  }
}

// ---------------- per-sample in-place transpose: [t][p] -> [p][t] (fp32) ------
__global__ void dyn_transp2(float* __restrict__ OUT)
{
  extern __shared__ float tile[];                 // [784][33] indexed p*33+t
  const int gm = blockIdx.x, tid = threadIdx.x;
  float* base = OUT + 40960 + (size_t)gm*SAMP_ELEMS;
  for (int idx = tid; idx < SAMP_ELEMS; idx += 256){
    int t = idx / 784, p = idx - t*784;
    tile[p*33 + t] = base[idx];                   // coalesced read, cf-free write
  }
  __syncthreads();
  for (int idx = tid; idx < SAMP_ELEMS; idx += 256)
    base[idx] = tile[idx];                        // cf-free read, coalesced write
}

// ---------------- launch ----------------
extern "C" void kernel_launch(void* const* d_in, const int* in_sizes, int n_in,
                              void* d_out, int out_size, void* d_ws, size_t ws_size,
                              hipStream_t stream)
{
  const float* X  = (const float*)d_in[0];
  const float* W0 = (const float*)d_in[1];
  const float* Ws = (const float*)d_in[2];
  const float* bs = (const float*)d_in[3];
  const float* Wc = (const float*)d_in[4];
  const float* bc = (const float*)d_in[5];
  unsigned short* WT = (unsigned short*)d_ws;
  float* OUT = (float*)d_out;

  (void)hipFuncSetAttribute((const void*)dyn_net,
        hipFuncAttributeMaxDynamicSharedMemorySize, LDS_TOTAL);
  (void)hipFuncSetAttribute((const void*)dyn_transp2,
        hipFuncAttributeMaxDynamicSharedMemorySize, TRANSP_LDS);

  dyn_prep<<<dim3(8192), dim3(256), 0, stream>>>(W0, Ws, WT);
  dyn_net<<<dim3(128), dim3(256), LDS_TOTAL, stream>>>(X, bs, Wc, bc, WT, OUT);
  dyn_transp2<<<dim3(2048), dim3(256), TRANSP_LDS, stream>>>(OUT);
}

// Round 4
// 1124.196 us; speedup vs baseline: 3.8956x; 1.1094x over previous
//
#include <hip/hip_runtime.h>
#include <stdint.h>

// ---------------------------------------------------------------------------
// DynResNet: u,v are (provably) constant; s += H*u^T dY v; x = u s v^T.
// Per step: Y = X*W^T (bf16 MFMA GEMM, W streamed global->VGPR as 1KB
// fragments), then per-sample MFMA chain R=dY*v, dS=u^T R, inc=u*dS*v^T,
// x += H*inc (fp32 regs). FP32 outputs.
//
// R4: 512 threads / 8 waves per block -> 2 waves/SIMD (was 1: all latency
// exposed). 49 real n-tiles split 7+6*7 across waves; per-tile kc order
// unchanged -> GEMM bit-identical to R3. Small stages: 2 samples/wave.
// Output transpose folded into dyn_net tail (dyn_transp2 deleted).
// dyn_prep vectorized (f32x4 loads, 16B stores).
// ---------------------------------------------------------------------------

#define H_STEP 0.001f

typedef float  f32x4  __attribute__((ext_vector_type(4)));
typedef __bf16 bf16x8 __attribute__((ext_vector_type(8)));
typedef unsigned short u16x8 __attribute__((ext_vector_type(8)));

__device__ __forceinline__ unsigned short f2bf(float f){
  unsigned u = __float_as_uint(f);
  u += 0x7FFFu + ((u >> 16) & 1u);        // RNE (finite data only)
  return (unsigned short)(u >> 16);
}
__device__ __forceinline__ float bf2f(unsigned short h){
  return __uint_as_float(((unsigned)h) << 16);
}

// W fragment tiling: 33 layers x 25 kc x 52 n-tiles; fragment = 1KB
// (64 lanes x 16B). lane(quad,col): n = p*16+col, k = kc*32+quad*8+j (j=0..7).
// Only tiles 0..48 are real (784 = 49*16); 49..51 are zero padding (unused).
#define NLAYER  33
#define NKC     25
#define NTILE   52
#define FRAG_B  1024
#define WT2_SHORTS ((size_t)NLAYER*NKC*NTILE*512)   // 21,964,800 (43.9 MB)

// LDS byte offsets (total 154,880 <= 163,840)
#define WBUF0_B 0          // 34,816: init scratch lo; dY [16][28][32] bf16
#define WBUF1_B 34816      // 34,816: init scratch hi; RT + G1 alias
#define XB_B    69632      // [16][808] bf16 GEMM A (x), K padded to 800
#define UA_B    95488      // [16][28][16] bf16  u[i][a]    (A for G1)
#define UA2_B   109824     // [16][10][40] bf16  u^T[a][i]  (A for dS)
#define VB2_B   122624     // [16][10][40] bf16  vh[b][j]   (B for R)
#define VTB_B   135424     // [16][28][16] bf16  v[j][b]    (B for G2)
#define DSB_B   149760     // [16][10][16] bf16  dS^T[b][a] (B for G1); logits scratch
#define LDS_TOTAL 154880
#define RT_B (WBUF1_B)
#define G1_B (WBUF1_B + 20480)

// per-sample transformed-output region: 784*33 fp32
#define SAMP_ELEMS (784*33)                      // 25872

// ---------------- prep: tile W0/Ws into bf16 B fragments (vectorized) --------
__global__ void dyn_prep(const float* __restrict__ W0, const float* __restrict__ Ws,
                         unsigned short* __restrict__ WT)
{
  const size_t totalv = WT2_SHORTS/8;            // 16B units
  for (size_t V = (size_t)blockIdx.x*256 + threadIdx.x; V < totalv; V += (size_t)gridDim.x*256){
    int lane = (int)(V & 63);
    size_t f = V >> 6;                           // fragment = (t*25+kc)*52+p
    int p  = (int)(f % NTILE);
    size_t r = f / NTILE;
    int kc = (int)(r % NKC);
    int t  = (int)(r / NKC);
    int n  = p*16 + (lane & 15);
    int k  = kc*32 + (lane >> 4)*8;
    u16x8 ov;
    if (n < 784 && k < 784){                     // 784%8==0 -> k<784 => k+7<784
      const float* W = (t == 0) ? W0 : (Ws + (size_t)(t-1)*614656);
      const float* src = W + (size_t)n*784 + k;
      f32x4 a = *(const f32x4*)(src);
      f32x4 b = *(const f32x4*)(src + 4);
      #pragma unroll
      for (int j = 0; j < 4; ++j){ ov[j] = f2bf(a[j]); ov[4+j] = f2bf(b[j]); }
    } else {
      #pragma unroll
      for (int j = 0; j < 8; ++j) ov[j] = 0;
    }
    *(u16x8*)(WT + (V<<3)) = ov;
  }
}

// ---------------- main persistent kernel (512 threads, 8 waves) --------------
__global__ void __launch_bounds__(512,2)
dyn_net(const float* __restrict__ X, const float* __restrict__ bs,
        const float* __restrict__ Wc, const float* __restrict__ bc,
        const unsigned short* __restrict__ WT, float* __restrict__ OUT)
{
  extern __shared__ char smem[];
  unsigned short* s16 = (unsigned short*)smem;
  const int tid = threadIdx.x;
  const int w = tid >> 6, lane = tid & 63, quad = lane >> 4, col = lane & 15;
  const int blk = blockIdx.x;

  for (int i = tid; i < LDS_TOTAL/4; i += 512) ((unsigned int*)smem)[i] = 0u;
  __syncthreads();

  // static per-sample operand buffers (u,v never change)
  for (int e = tid; e < 16*28*16; e += 512){            // uA [m][i][a16]
    int m = e / 448, r = e % 448, i = r >> 4, a = r & 15;
    float v = (a < 10) ? X[(size_t)(blk*16+m)*840 + i*10 + a] : 0.f;
    s16[UA_B/2 + e] = f2bf(v);
  }
  for (int e = tid; e < 16*10*40; e += 512){            // uA2 [m][a][i40]
    int m = e / 400, r = e % 400, a = r / 40, i = r % 40;
    float v = (i < 28) ? X[(size_t)(blk*16+m)*840 + i*10 + a] : 0.f;
    s16[UA2_B/2 + e] = f2bf(v);
  }
  for (int e = tid; e < 16*10*40; e += 512){            // vB2 [m][b][j40] = vh[b][j]
    int m = e / 400, r = e % 400, b = r / 40, j = r % 40;
    float v = (j < 28) ? X[(size_t)(blk*16+m)*840 + 560 + b*28 + j] : 0.f;
    s16[VB2_B/2 + e] = f2bf(v);
  }
  for (int e = tid; e < 16*28*16; e += 512){            // vTB [m][j][b16] = vh[b][j]
    int m = e / 448, r = e % 448, j = r >> 4, b = r & 15;
    float v = (b < 10) ? X[(size_t)(blk*16+m)*840 + 560 + b*28 + j] : 0.f;
    s16[VTB_B/2 + e] = f2bf(v);
  }
  __syncthreads();

  // x_init = u*s0*vh in exact fp32; xr = register fp32 x master.
  // Per-wave scratch: 8 waves x 8KB = 64KB over WBUF0+WBUF1 (<=69,632).
  float xr[2][2][2][4];
  for (int q = 0; q < 2; ++q){
    int m = w*2 + q;
    int gm = blk*16 + m;
    float* scr = (float*)smem + w*2048;                 // 8KB/wave scratch
    for (int e = lane; e < 840; e += 64) scr[e] = X[(size_t)gm*840 + e];
    __syncthreads();
    float* T = scr + 840;                               // T = u@s0 (28x10)
    for (int it = 0; it < 5; ++it){
      int e = lane + it*64;
      if (e < 280){
        int i = e / 10, b = e % 10;
        float acc = 0.f;
        for (int a = 0; a < 10; ++a) acc += scr[i*10+a] * scr[280 + a*10 + b];
        T[e] = acc;
      }
    }
    __syncthreads();
    #pragma unroll
    for (int mt = 0; mt < 2; ++mt)
    #pragma unroll
    for (int nt = 0; nt < 2; ++nt)
    #pragma unroll
    for (int r = 0; r < 4; ++r){
      int i = mt*16 + quad*4 + r;
      int j = nt*16 + col;
      float acc = 0.f;
      if (i < 28 && j < 28){
        for (int b = 0; b < 10; ++b) acc += T[i*10+b] * scr[560 + b*28 + j];
        s16[XB_B/2 + m*808 + i*28 + j] = f2bf(acc);
      }
      xr[q][mt][nt][r] = acc;
    }
    __syncthreads();
  }

  // Re-zero WBUF0+WBUF1 (dY/RT/G1 regions incl. padding): the fp32 init
  // scratch left NaN-pattern bf16 garbage; MFMA A-reads of padding need 0.
  for (int i = tid; i < (WBUF1_B + 34816)/4; i += 512)
    ((unsigned int*)smem)[i] = 0u;
  __syncthreads();

  const float Hs = H_STEP;
  const int CNT = (w == 0) ? 7 : 6;                     // real tiles 0..48
  const int P0  = (w == 0) ? 0 : 7 + (w-1)*6;

  for (int t = 0; t < NLAYER; ++t){
    // --- GEMM: Y = x @ W^T, W streamed global->VGPR, no barriers ---
    const char* WLb = (const char*)WT
        + ((size_t)t*NKC*NTILE + (size_t)P0)*FRAG_B + (size_t)lane*16;
    // fragment (kc,p): WLb + (kc*NTILE + p)*FRAG_B

    f32x4 acc[7];
    #pragma unroll
    for (int p = 0; p < 7; ++p) acc[p] = (f32x4){0.f,0.f,0.f,0.f};

    float biasr[7];                                     // hoisted bias loads
    #pragma unroll
    for (int p = 0; p < 7; ++p){
      float bv = 0.f;
      if (p < CNT && t > 0){
        int n = (P0+p)*16 + col;
        bv = bs[(size_t)(t-1)*784 + n];
      }
      biasr[p] = bv;
    }

    bf16x8 wfA[7], wfB[7];
    #pragma unroll
    for (int p = 0; p < 7; ++p)
      if (p < CNT) wfA[p] = *(const bf16x8*)(WLb + (size_t)p*FRAG_B);

    #pragma unroll 1
    for (int kc = 0; kc < NKC; kc += 2){
      if (kc+1 < NKC){
        const char* nb = WLb + (size_t)(kc+1)*(NTILE*FRAG_B);
        #pragma unroll
        for (int p = 0; p < 7; ++p)
          if (p < CNT) wfB[p] = *(const bf16x8*)(nb + (size_t)p*FRAG_B);
      }
      bf16x8 af = *(const bf16x8*)(s16 + XB_B/2 + col*808 + kc*32 + quad*8);
      #pragma unroll
      for (int p = 0; p < 7; ++p)
        if (p < CNT)
          acc[p] = __builtin_amdgcn_mfma_f32_16x16x32_bf16(af, wfA[p], acc[p], 0,0,0);
      if (kc+1 < NKC){
        if (kc+2 < NKC){
          const char* nb2 = WLb + (size_t)(kc+2)*(NTILE*FRAG_B);
          #pragma unroll
          for (int p = 0; p < 7; ++p)
            if (p < CNT) wfA[p] = *(const bf16x8*)(nb2 + (size_t)p*FRAG_B);
        }
        bf16x8 af2 = *(const bf16x8*)(s16 + XB_B/2 + col*808 + (kc+1)*32 + quad*8);
        #pragma unroll
        for (int p = 0; p < 7; ++p)
          if (p < CNT)
            acc[p] = __builtin_amdgcn_mfma_f32_16x16x32_bf16(af2, wfB[p], acc[p], 0,0,0);
      }
    }

    // epilogue: bias/relu, write dY bf16 into WBUF0
    unsigned short* dy = (unsigned short*)(smem + WBUF0_B);
    #pragma unroll
    for (int p = 0; p < 7; ++p){
      if (p < CNT){
        int n = (P0+p)*16 + col;                        // always < 784
        int i = n / 28, j = n % 28;
        #pragma unroll
        for (int r = 0; r < 4; ++r){
          float y = acc[p][r] + biasr[p];
          if (t > 0) y = fmaxf(y, 0.f);
          dy[(quad*4+r)*896 + i*32 + j] = f2bf(y);
        }
      }
    }
    __syncthreads();                                    // dY visible to all waves

    // small stages per wave (samples w*2, w*2+1)
    #pragma unroll 1
    for (int q = 0; q < 2; ++q){
      int m = w*2 + q;
      bf16x8 zfrag = {0,0,0,0,0,0,0,0};
      const unsigned short* dys = dy + m*896;
      // R = dY @ v  -> RT[b][i]
      bf16x8 bfA = zfrag;
      if (col < 10) bfA = *(const bf16x8*)(s16 + VB2_B/2 + m*400 + col*40 + quad*8);
      unsigned short* rt = s16 + RT_B/2 + m*640;
      #pragma unroll
      for (int mt = 0; mt < 2; ++mt){
        bf16x8 afA = *(const bf16x8*)(dys + (col + 16*mt)*32 + quad*8);
        f32x4 cR = {0.f,0.f,0.f,0.f};
        cR = __builtin_amdgcn_mfma_f32_16x16x32_bf16(afA, bfA, cR, 0,0,0);
        int i0 = mt*16 + quad*4;
        if (i0 < 28){
          unsigned short* p = rt + col*40 + i0;
          p[0]=f2bf(cR[0]); p[1]=f2bf(cR[1]); p[2]=f2bf(cR[2]); p[3]=f2bf(cR[3]);
        }
      }
      // dS = u^T @ R
      bf16x8 afB = zfrag;
      if (col < 10) afB = *(const bf16x8*)(s16 + UA2_B/2 + m*400 + col*40 + quad*8);
      bf16x8 bfB = *(const bf16x8*)(rt + col*40 + quad*8);
      f32x4 cS = {0.f,0.f,0.f,0.f};
      cS = __builtin_amdgcn_mfma_f32_16x16x32_bf16(afB, bfB, cS, 0,0,0);
      unsigned short* dsb = s16 + DSB_B/2 + m*160;      // dS^T[b][a]
      if (col < 10){
        unsigned short* p = dsb + col*16 + quad*4;
        p[0]=f2bf(cS[0]); p[1]=f2bf(cS[1]); p[2]=f2bf(cS[2]); p[3]=f2bf(cS[3]);
      }
      // G1 = u @ dS  (K=16 via quads 0,1)
      bf16x8 bfG = zfrag;
      if (quad < 2 && col < 10) bfG = *(const bf16x8*)(dsb + col*16 + quad*8);
      const unsigned short* ua = s16 + UA_B/2 + m*448;
      unsigned short* g1 = s16 + G1_B/2 + m*448;
      #pragma unroll
      for (int mt = 0; mt < 2; ++mt){
        int row = col + 16*mt;
        bf16x8 afG = zfrag;
        if (quad < 2 && row < 28) afG = *(const bf16x8*)(ua + row*16 + quad*8);
        f32x4 cG = {0.f,0.f,0.f,0.f};
        cG = __builtin_amdgcn_mfma_f32_16x16x32_bf16(afG, bfG, cG, 0,0,0);
        int i0 = mt*16 + quad*4;
        #pragma unroll
        for (int r = 0; r < 4; ++r)
          if (i0 + r < 28) g1[(i0+r)*16 + col] = f2bf(cG[r]);
      }
      // G2 = G1 @ v^T ; x += H*G2 (fp32 regs); write xb + t-major out
      const unsigned short* vtb = s16 + VTB_B/2 + m*448;
      bf16x8 bt[2];
      #pragma unroll
      for (int nt = 0; nt < 2; ++nt){
        bt[nt] = zfrag;
        int n = col + 16*nt;
        if (quad < 2 && n < 28) bt[nt] = *(const bf16x8*)(vtb + n*16 + quad*8);
      }
      int gm = blk*16 + m;
      float* outg = OUT + 40960 + (size_t)gm*SAMP_ELEMS + (size_t)t*784;
      #pragma unroll
      for (int mt = 0; mt < 2; ++mt){
        int row = col + 16*mt;
        bf16x8 afX = zfrag;
        if (quad < 2 && row < 28) afX = *(const bf16x8*)(g1 + row*16 + quad*8);
        #pragma unroll
        for (int nt = 0; nt < 2; ++nt){
          f32x4 cX = {0.f,0.f,0.f,0.f};
          cX = __builtin_amdgcn_mfma_f32_16x16x32_bf16(afX, bt[nt], cX, 0,0,0);
          int i0 = mt*16 + quad*4;
          int j = nt*16 + col;
          if (j < 28){
            #pragma unroll
            for (int r = 0; r < 4; ++r){
              int i = i0 + r;
              if (i < 28){
                float xn = xr[q][mt][nt][r] + Hs * cX[r];
                xr[q][mt][nt][r] = xn;
                s16[XB_B/2 + m*808 + i*28 + j] = f2bf(xn);
                outg[i*28 + j] = xn;
              }
            }
          }
        }
      }
    }
    __syncthreads();                                    // step end (XB handoff)
  }

  // classifier + softmax (fp32 outputs)
  float* lg = (float*)(smem + DSB_B);
  if (tid < 160){
    int m = tid / 10, c = tid % 10;
    float accv = bc[c];
    const unsigned short* xbp = s16 + XB_B/2 + m*808;
    for (int p = 0; p < 784; ++p)
      accv += bf2f(xbp[p]) * Wc[(size_t)c*784 + p];
    lg[tid] = accv;
  }
  __syncthreads();
  if (tid < 16){
    int gm = blk*16 + tid;
    float* l = lg + tid*10;
    float mx = l[0];
    for (int c2 = 1; c2 < 10; ++c2) mx = fmaxf(mx, l[c2]);
    float s = 0.f, ex[10];
    for (int c2 = 0; c2 < 10; ++c2){ ex[c2] = expf(l[c2]-mx); s += ex[c2]; }
    float inv = 1.f / s;
    for (int c2 = 0; c2 < 10; ++c2){
      OUT[(size_t)gm*10 + c2]         = ex[c2]*inv;   // X_predicted (fp32)
      OUT[20480 + (size_t)gm*10 + c2] = l[c2];        // X_classified (fp32)
    }
  }
  __syncthreads();

  // folded transpose: per sample [t][p] -> [p][t] in place (L2/L3-hot data).
  // Tile [784][33] fp32 at smem+0 (103,488 B); stride 33 -> bank-conflict-free.
  {
    float* tile = (float*)smem;
    for (int m = 0; m < 16; ++m){
      float* base = OUT + 40960 + (size_t)(blk*16 + m)*SAMP_ELEMS;
      for (int idx = tid; idx < SAMP_ELEMS; idx += 512){
        int tt = idx / 784, pp = idx - tt*784;
        tile[pp*33 + tt] = base[idx];                 // coalesced read
      }
      __syncthreads();
      for (int idx = tid; idx < SAMP_ELEMS; idx += 512)
        base[idx] = tile[idx];                        // coalesced write
      __syncthreads();
    }
  }
}

// ---------------- launch ----------------
extern "C" void kernel_launch(void* const* d_in, const int* in_sizes, int n_in,
                              void* d_out, int out_size, void* d_ws, size_t ws_size,
                              hipStream_t stream)
{
  const float* X  = (const float*)d_in[0];
  const float* W0 = (const float*)d_in[1];
  const float* Ws = (const float*)d_in[2];
  const float* bs = (const float*)d_in[3];
  const float* Wc = (const float*)d_in[4];
  const float* bc = (const float*)d_in[5];
  unsigned short* WT = (unsigned short*)d_ws;
  float* OUT = (float*)d_out;

  (void)hipFuncSetAttribute((const void*)dyn_net,
        hipFuncAttributeMaxDynamicSharedMemorySize, LDS_TOTAL);

  dyn_prep<<<dim3(8192), dim3(256), 0, stream>>>(W0, Ws, WT);
  dyn_net<<<dim3(128), dim3(512), LDS_TOTAL, stream>>>(X, bs, Wc, bc, WT, OUT);
}

// Round 5
// 858.579 us; speedup vs baseline: 5.1008x; 1.3094x over previous
//
#include <hip/hip_runtime.h>
#include <stdint.h>

// ---------------------------------------------------------------------------
// DynResNet: u,v are (provably) constant; s += H*u^T dY v; x = u s v^T.
// Per step: Y = X*W^T (bf16 MFMA GEMM, W streamed global->VGPR as 1KB
// fragments), then per-sample MFMA chain R=dY*v, dS=u^T R, inc=u*dS*v^T,
// x += H*inc (fp32 regs). FP32 outputs.
//
// R5: (a) X_transformed staged as COALESCED bf16 t-major strips in the upper
// half of each sample's own OUT region (in-loop scattered fp32 stores with
// 2.2x RMW amp deleted); tail transpose reads bf16 (L2/L3-hot) and writes
// final fp32 [p][t] with aligned f32x4 stores. (b) 1024 threads / 16 waves
// -> 4 waves/SIMD (was 2); 49 n-tiles split 4+3*15, per-tile kc order
// unchanged -> GEMM bit-identical; 1 sample/wave small stages.
// ---------------------------------------------------------------------------

#define H_STEP 0.001f

typedef float  f32x4  __attribute__((ext_vector_type(4)));
typedef __bf16 bf16x8 __attribute__((ext_vector_type(8)));
typedef unsigned short u16x8 __attribute__((ext_vector_type(8)));

__device__ __forceinline__ unsigned short f2bf(float f){
  unsigned u = __float_as_uint(f);
  u += 0x7FFFu + ((u >> 16) & 1u);        // RNE (finite data only)
  return (unsigned short)(u >> 16);
}
__device__ __forceinline__ float bf2f(unsigned short h){
  return __uint_as_float(((unsigned)h) << 16);
}

// W fragment tiling: 33 layers x 25 kc x 52 n-tiles; fragment = 1KB
// (64 lanes x 16B). lane(quad,col): n = p*16+col, k = kc*32+quad*8+j (j=0..7).
// Only tiles 0..48 are real (784 = 49*16); 49..51 are zero padding (unused).
#define NLAYER  33
#define NKC     25
#define NTILE   52
#define FRAG_B  1024
#define WT2_SHORTS ((size_t)NLAYER*NKC*NTILE*512)   // 21,964,800 (43.9 MB)

// LDS byte offsets (total 154,880 <= 163,840)
#define WBUF0_B 0          // 34,816: init scratch lo; dY [16][28][32] bf16
#define WBUF1_B 34816      // 34,816: init scratch hi; RT + G1 alias
#define XB_B    69632      // [16][808] bf16 GEMM A (x), K padded to 800
#define UA_B    95488      // [16][28][16] bf16  u[i][a]    (A for G1)
#define UA2_B   109824     // [16][10][40] bf16  u^T[a][i]  (A for dS)
#define VB2_B   122624     // [16][10][40] bf16  vh[b][j]   (B for R)
#define VTB_B   135424     // [16][28][16] bf16  v[j][b]    (B for G2)
#define DSB_B   149760     // [16][10][16] bf16  dS^T[b][a] (B for G1); logits scratch
#define LDS_TOTAL 154880
#define RT_B (WBUF1_B)
#define G1_B (WBUF1_B + 20480)

// per-sample transformed-output region: 784*33 fp32 = 25,872 floats.
// bf16 staging strip parked at float offset 12,928 within the region
// (bytes 51,712..103,455; 33*1568 = 51,744 B; 16B-aligned everywhere).
#define SAMP_ELEMS (784*33)                      // 25872
#define XTR_BASE   40960
#define STG_FOFF   12928

// ---------------- prep: tile W0/Ws into bf16 B fragments (vectorized) --------
__global__ void dyn_prep(const float* __restrict__ W0, const float* __restrict__ Ws,
                         unsigned short* __restrict__ WT)
{
  const size_t totalv = WT2_SHORTS/8;            // 16B units
  for (size_t V = (size_t)blockIdx.x*256 + threadIdx.x; V < totalv; V += (size_t)gridDim.x*256){
    int lane = (int)(V & 63);
    size_t f = V >> 6;                           // fragment = (t*25+kc)*52+p
    int p  = (int)(f % NTILE);
    size_t r = f / NTILE;
    int kc = (int)(r % NKC);
    int t  = (int)(r / NKC);
    int n  = p*16 + (lane & 15);
    int k  = kc*32 + (lane >> 4)*8;
    u16x8 ov;
    if (n < 784 && k < 784){                     // 784%8==0 -> k<784 => k+7<784
      const float* W = (t == 0) ? W0 : (Ws + (size_t)(t-1)*614656);
      const float* src = W + (size_t)n*784 + k;
      f32x4 a = *(const f32x4*)(src);
      f32x4 b = *(const f32x4*)(src + 4);
      #pragma unroll
      for (int j = 0; j < 4; ++j){ ov[j] = f2bf(a[j]); ov[4+j] = f2bf(b[j]); }
    } else {
      #pragma unroll
      for (int j = 0; j < 8; ++j) ov[j] = 0;
    }
    *(u16x8*)(WT + (V<<3)) = ov;
  }
}

// ---------------- main persistent kernel (1024 threads, 16 waves) ------------
__global__ void __launch_bounds__(1024,4)
dyn_net(const float* __restrict__ X, const float* __restrict__ bs,
        const float* __restrict__ Wc, const float* __restrict__ bc,
        const unsigned short* __restrict__ WT, float* __restrict__ OUT)
{
  extern __shared__ char smem[];
  unsigned short* s16 = (unsigned short*)smem;
  const int tid = threadIdx.x;
  const int w = tid >> 6, lane = tid & 63, quad = lane >> 4, col = lane & 15;
  const int blk = blockIdx.x;
  const int m  = w;                               // one sample per wave
  const int gm = blk*16 + m;

  for (int i = tid; i < LDS_TOTAL/4; i += 1024) ((unsigned int*)smem)[i] = 0u;
  __syncthreads();

  // static per-sample operand buffers (u,v never change)
  for (int e = tid; e < 16*28*16; e += 1024){           // uA [m][i][a16]
    int mm = e / 448, r = e % 448, i = r >> 4, a = r & 15;
    float v = (a < 10) ? X[(size_t)(blk*16+mm)*840 + i*10 + a] : 0.f;
    s16[UA_B/2 + e] = f2bf(v);
  }
  for (int e = tid; e < 16*10*40; e += 1024){           // uA2 [m][a][i40]
    int mm = e / 400, r = e % 400, a = r / 40, i = r % 40;
    float v = (i < 28) ? X[(size_t)(blk*16+mm)*840 + i*10 + a] : 0.f;
    s16[UA2_B/2 + e] = f2bf(v);
  }
  for (int e = tid; e < 16*10*40; e += 1024){           // vB2 [m][b][j40] = vh[b][j]
    int mm = e / 400, r = e % 400, b = r / 40, j = r % 40;
    float v = (j < 28) ? X[(size_t)(blk*16+mm)*840 + 560 + b*28 + j] : 0.f;
    s16[VB2_B/2 + e] = f2bf(v);
  }
  for (int e = tid; e < 16*28*16; e += 1024){           // vTB [m][j][b16] = vh[b][j]
    int mm = e / 448, r = e % 448, j = r >> 4, b = r & 15;
    float v = (b < 10) ? X[(size_t)(blk*16+mm)*840 + 560 + b*28 + j] : 0.f;
    s16[VTB_B/2 + e] = f2bf(v);
  }
  __syncthreads();

  // x_init = u*s0*vh in exact fp32; xr = register fp32 x master.
  // Per-wave scratch 844 floats (u 0..279 as part of 0..559 with s; T at 560..839);
  // 16 waves * 3376 B = 54,016 B < 69,632 -> stays inside WBUF0+WBUF1.
  // vh read from global into registers. No barriers needed (wave-local).
  float xr[2][2][4];
  {
    float* scr = (float*)smem + w*844;
    for (int e = lane; e < 560; e += 64) scr[e] = X[(size_t)gm*840 + e];
    float vhr[2][10];
    #pragma unroll
    for (int nt = 0; nt < 2; ++nt){
      int j = nt*16 + col;
      #pragma unroll
      for (int b = 0; b < 10; ++b)
        vhr[nt][b] = (j < 28) ? X[(size_t)gm*840 + 560 + b*28 + j] : 0.f;
    }
    #pragma unroll
    for (int it = 0; it < 5; ++it){
      int e = lane + it*64;
      if (e < 280){
        int i = e / 10, b = e % 10;
        float acc = 0.f;
        for (int a = 0; a < 10; ++a) acc += scr[i*10+a] * scr[280 + a*10 + b];
        scr[560 + e] = acc;                             // T = u@s0 (28x10)
      }
    }
    #pragma unroll
    for (int mt = 0; mt < 2; ++mt)
    #pragma unroll
    for (int nt = 0; nt < 2; ++nt)
    #pragma unroll
    for (int r = 0; r < 4; ++r){
      int i = mt*16 + quad*4 + r;
      int j = nt*16 + col;
      float acc = 0.f;
      if (i < 28 && j < 28){
        for (int b = 0; b < 10; ++b) acc += scr[560 + i*10 + b] * vhr[nt][b];
        s16[XB_B/2 + m*808 + i*28 + j] = f2bf(acc);
      }
      xr[mt][nt][r] = acc;
    }
  }
  __syncthreads();

  // Re-zero WBUF0+WBUF1 (dY/RT/G1 incl. padding): the fp32 init scratch left
  // NaN-pattern bf16 garbage; MFMA A-reads of padding need 0.
  for (int i = tid; i < (WBUF1_B + 34816)/4; i += 1024)
    ((unsigned int*)smem)[i] = 0u;
  __syncthreads();

  const float Hs = H_STEP;
  const int CNT = (w == 0) ? 4 : 3;                     // real tiles 0..48
  const int P0  = (w == 0) ? 0 : 4 + (w-1)*3;

  for (int t = 0; t < NLAYER; ++t){
    // --- GEMM: Y = x @ W^T, W streamed global->VGPR, no barriers ---
    const char* WLb = (const char*)WT
        + ((size_t)t*NKC*NTILE + (size_t)P0)*FRAG_B + (size_t)lane*16;

    f32x4 acc[4];
    #pragma unroll
    for (int p = 0; p < 4; ++p) acc[p] = (f32x4){0.f,0.f,0.f,0.f};

    float biasr[4];                                     // hoisted bias loads
    #pragma unroll
    for (int p = 0; p < 4; ++p){
      float bv = 0.f;
      if (p < CNT && t > 0){
        int n = (P0+p)*16 + col;
        bv = bs[(size_t)(t-1)*784 + n];
      }
      biasr[p] = bv;
    }

    bf16x8 wfA[4], wfB[4];
    #pragma unroll
    for (int p = 0; p < 4; ++p)
      if (p < CNT) wfA[p] = *(const bf16x8*)(WLb + (size_t)p*FRAG_B);

    #pragma unroll 1
    for (int kc = 0; kc < NKC; kc += 2){
      if (kc+1 < NKC){
        const char* nb = WLb + (size_t)(kc+1)*(NTILE*FRAG_B);
        #pragma unroll
        for (int p = 0; p < 4; ++p)
          if (p < CNT) wfB[p] = *(const bf16x8*)(nb + (size_t)p*FRAG_B);
      }
      bf16x8 af = *(const bf16x8*)(s16 + XB_B/2 + col*808 + kc*32 + quad*8);
      #pragma unroll
      for (int p = 0; p < 4; ++p)
        if (p < CNT)
          acc[p] = __builtin_amdgcn_mfma_f32_16x16x32_bf16(af, wfA[p], acc[p], 0,0,0);
      if (kc+1 < NKC){
        if (kc+2 < NKC){
          const char* nb2 = WLb + (size_t)(kc+2)*(NTILE*FRAG_B);
          #pragma unroll
          for (int p = 0; p < 4; ++p)
            if (p < CNT) wfA[p] = *(const bf16x8*)(nb2 + (size_t)p*FRAG_B);
        }
        bf16x8 af2 = *(const bf16x8*)(s16 + XB_B/2 + col*808 + (kc+1)*32 + quad*8);
        #pragma unroll
        for (int p = 0; p < 4; ++p)
          if (p < CNT)
            acc[p] = __builtin_amdgcn_mfma_f32_16x16x32_bf16(af2, wfB[p], acc[p], 0,0,0);
      }
    }

    // epilogue: bias/relu, write dY bf16 into WBUF0 (all 16 samples per wave)
    unsigned short* dy = (unsigned short*)(smem + WBUF0_B);
    #pragma unroll
    for (int p = 0; p < 4; ++p){
      if (p < CNT){
        int n = (P0+p)*16 + col;                        // always < 784
        int i = n / 28, j = n % 28;
        #pragma unroll
        for (int r = 0; r < 4; ++r){
          float y = acc[p][r] + biasr[p];
          if (t > 0) y = fmaxf(y, 0.f);
          dy[(quad*4+r)*896 + i*32 + j] = f2bf(y);
        }
      }
    }
    __syncthreads();                                    // dY visible to all waves

    // small stages: one sample per wave (m = w)
    {
      bf16x8 zfrag = {0,0,0,0,0,0,0,0};
      const unsigned short* dys = dy + m*896;
      // R = dY @ v  -> RT[b][i]
      bf16x8 bfA = zfrag;
      if (col < 10) bfA = *(const bf16x8*)(s16 + VB2_B/2 + m*400 + col*40 + quad*8);
      unsigned short* rt = s16 + RT_B/2 + m*640;
      #pragma unroll
      for (int mt = 0; mt < 2; ++mt){
        bf16x8 afA = *(const bf16x8*)(dys + (col + 16*mt)*32 + quad*8);
        f32x4 cR = {0.f,0.f,0.f,0.f};
        cR = __builtin_amdgcn_mfma_f32_16x16x32_bf16(afA, bfA, cR, 0,0,0);
        int i0 = mt*16 + quad*4;
        if (i0 < 28){
          unsigned short* p = rt + col*40 + i0;
          p[0]=f2bf(cR[0]); p[1]=f2bf(cR[1]); p[2]=f2bf(cR[2]); p[3]=f2bf(cR[3]);
        }
      }
      // dS = u^T @ R
      bf16x8 afB = zfrag;
      if (col < 10) afB = *(const bf16x8*)(s16 + UA2_B/2 + m*400 + col*40 + quad*8);
      bf16x8 bfB = *(const bf16x8*)(rt + col*40 + quad*8);
      f32x4 cS = {0.f,0.f,0.f,0.f};
      cS = __builtin_amdgcn_mfma_f32_16x16x32_bf16(afB, bfB, cS, 0,0,0);
      unsigned short* dsb = s16 + DSB_B/2 + m*160;      // dS^T[b][a]
      if (col < 10){
        unsigned short* p = dsb + col*16 + quad*4;
        p[0]=f2bf(cS[0]); p[1]=f2bf(cS[1]); p[2]=f2bf(cS[2]); p[3]=f2bf(cS[3]);
      }
      // G1 = u @ dS  (K=16 via quads 0,1)
      bf16x8 bfG = zfrag;
      if (quad < 2 && col < 10) bfG = *(const bf16x8*)(dsb + col*16 + quad*8);
      const unsigned short* ua = s16 + UA_B/2 + m*448;
      unsigned short* g1 = s16 + G1_B/2 + m*448;
      #pragma unroll
      for (int mt = 0; mt < 2; ++mt){
        int row = col + 16*mt;
        bf16x8 afG = zfrag;
        if (quad < 2 && row < 28) afG = *(const bf16x8*)(ua + row*16 + quad*8);
        f32x4 cG = {0.f,0.f,0.f,0.f};
        cG = __builtin_amdgcn_mfma_f32_16x16x32_bf16(afG, bfG, cG, 0,0,0);
        int i0 = mt*16 + quad*4;
        #pragma unroll
        for (int r = 0; r < 4; ++r)
          if (i0 + r < 28) g1[(i0+r)*16 + col] = f2bf(cG[r]);
      }
      // G2 = G1 @ v^T ; x += H*G2 (fp32 regs); update XB (bf16)
      const unsigned short* vtb = s16 + VTB_B/2 + m*448;
      bf16x8 bt[2];
      #pragma unroll
      for (int nt = 0; nt < 2; ++nt){
        bt[nt] = zfrag;
        int n = col + 16*nt;
        if (quad < 2 && n < 28) bt[nt] = *(const bf16x8*)(vtb + n*16 + quad*8);
      }
      #pragma unroll
      for (int mt = 0; mt < 2; ++mt){
        int row = col + 16*mt;
        bf16x8 afX = zfrag;
        if (quad < 2 && row < 28) afX = *(const bf16x8*)(g1 + row*16 + quad*8);
        #pragma unroll
        for (int nt = 0; nt < 2; ++nt){
          f32x4 cX = {0.f,0.f,0.f,0.f};
          cX = __builtin_amdgcn_mfma_f32_16x16x32_bf16(afX, bt[nt], cX, 0,0,0);
          int i0 = mt*16 + quad*4;
          int j = nt*16 + col;
          if (j < 28){
            #pragma unroll
            for (int r = 0; r < 4; ++r){
              int i = i0 + r;
              if (i < 28){
                float xn = xr[mt][nt][r] + Hs * cX[r];
                xr[mt][nt][r] = xn;
                s16[XB_B/2 + m*808 + i*28 + j] = f2bf(xn);
              }
            }
          }
        }
      }
      // coalesced bf16 staging copy: XB[m][0..783] -> OUT staging strip [t][784]
      const unsigned short* xb = s16 + XB_B/2 + m*808;
      unsigned short* stg = (unsigned short*)(OUT + XTR_BASE
                           + (size_t)gm*SAMP_ELEMS + STG_FOFF) + (size_t)t*784;
      u16x8 v0 = *(const u16x8*)(xb + lane*8);
      *(u16x8*)(stg + lane*8) = v0;
      if (lane < 34){
        u16x8 v1 = *(const u16x8*)(xb + 512 + lane*8);
        *(u16x8*)(stg + 512 + lane*8) = v1;
      }
    }
    __syncthreads();                                    // step end (XB handoff)
  }

  // classifier + softmax (fp32 outputs)
  float* lg = (float*)(smem + DSB_B);
  if (tid < 160){
    int mm = tid / 10, c = tid % 10;
    float accv = bc[c];
    const unsigned short* xbp = s16 + XB_B/2 + mm*808;
    for (int p = 0; p < 784; ++p)
      accv += bf2f(xbp[p]) * Wc[(size_t)c*784 + p];
    lg[tid] = accv;
  }
  __syncthreads();
  if (tid < 16){
    int gm2 = blk*16 + tid;
    float* l = lg + tid*10;
    float mx = l[0];
    for (int c2 = 1; c2 < 10; ++c2) mx = fmaxf(mx, l[c2]);
    float s = 0.f, ex[10];
    for (int c2 = 0; c2 < 10; ++c2){ ex[c2] = expf(l[c2]-mx); s += ex[c2]; }
    float inv = 1.f / s;
    for (int c2 = 0; c2 < 10; ++c2){
      OUT[(size_t)gm2*10 + c2]         = ex[c2]*inv;  // X_predicted (fp32)
      OUT[20480 + (size_t)gm2*10 + c2] = l[c2];       // X_classified (fp32)
    }
  }
  __syncthreads();

  // tail: per sample, bf16 staging [t][p] -> fp32 [p][t] in place.
  // LDS tile [784][33] fp32 (103,488 B); stride 33 -> bank-conflict-free.
  // Staging read happens before the fp32 writes cover it (same block).
  {
    float* tile = (float*)smem;
    for (int mm = 0; mm < 16; ++mm){
      size_t g2 = (size_t)(blk*16 + mm);
      const unsigned short* stg = (const unsigned short*)
          (OUT + XTR_BASE + g2*SAMP_ELEMS + STG_FOFF);
      for (int id2 = tid; id2 < SAMP_ELEMS/2; id2 += 1024){
        unsigned vv = *(const unsigned*)(stg + id2*2);
        int idx = id2*2;
        int tt = idx / 784, pp = idx - tt*784;          // 784 even: pair same t
        tile[pp*33 + tt]     = bf2f((unsigned short)(vv & 0xFFFFu));
        tile[(pp+1)*33 + tt] = bf2f((unsigned short)(vv >> 16));
      }
      __syncthreads();
      float* base = OUT + XTR_BASE + g2*SAMP_ELEMS;
      for (int id4 = tid; id4 < SAMP_ELEMS/4; id4 += 1024)
        *(f32x4*)(base + id4*4) = *(const f32x4*)(tile + id4*4);
      __syncthreads();
    }
  }
}

// ---------------- launch ----------------
extern "C" void kernel_launch(void* const* d_in, const int* in_sizes, int n_in,
                              void* d_out, int out_size, void* d_ws, size_t ws_size,
                              hipStream_t stream)
{
  const float* X  = (const float*)d_in[0];
  const float* W0 = (const float*)d_in[1];
  const float* Ws = (const float*)d_in[2];
  const float* bs = (const float*)d_in[3];
  const float* Wc = (const float*)d_in[4];
  const float* bc = (const float*)d_in[5];
  unsigned short* WT = (unsigned short*)d_ws;
  float* OUT = (float*)d_out;

  (void)hipFuncSetAttribute((const void*)dyn_net,
        hipFuncAttributeMaxDynamicSharedMemorySize, LDS_TOTAL);

  dyn_prep<<<dim3(8192), dim3(256), 0, stream>>>(W0, Ws, WT);
  dyn_net<<<dim3(128), dim3(1024), LDS_TOTAL, stream>>>(X, bs, Wc, bc, WT, OUT);
}